// Round 3
// baseline (1504.546 us; speedup 1.0000x reference)
//
#include <hip/hip_runtime.h>
#include <math.h>

#define T_TOTAL 32000
#define BATCH 4
#define TT 64
#define TTF 32
#define ZCHUNK 15
#define ZSLOT_ELEMS ((size_t)BATCH * T_TOTAL * 64)

typedef __bf16 bf16x8 __attribute__((ext_vector_type(8)));
typedef float f32x4 __attribute__((ext_vector_type(4)));
typedef unsigned int uint4v __attribute__((ext_vector_type(4)));
typedef unsigned int uint2v __attribute__((ext_vector_type(2)));

__device__ __forceinline__ unsigned short f2b(float f) {
    unsigned int u = __float_as_uint(f);
    u += 0x7FFFu + ((u >> 16) & 1u);
    return (unsigned short)(u >> 16);
}
__device__ __forceinline__ unsigned int f2b2(float lo, float hi) {
    return (unsigned int)f2b(lo) | ((unsigned int)f2b(hi) << 16);
}
__device__ __forceinline__ bf16x8 ld_bf8(const unsigned short* p) {
    return __builtin_bit_cast(bf16x8, *(const uint4v*)p);
}
__device__ __forceinline__ float fast_sigmoid(float x) {
    return __builtin_amdgcn_rcpf(1.0f + __expf(-x));
}
__device__ __forceinline__ float fast_tanh(float x) {
    return 1.0f - 2.0f * __builtin_amdgcn_rcpf(1.0f + __expf(2.0f * x));
}

// ---------------- weight packing (fp32 -> bf16, fused/padded layouts) ----------
__global__ void k_pack(const float* __restrict__ conv_w, const float* __restrict__ cond_w,
                       const float* __restrict__ skip_w, const float* __restrict__ out_w,
                       const float* __restrict__ first_w, const float* __restrict__ last1_w,
                       const float* __restrict__ last2_w, const float* __restrict__ skip_b,
                       unsigned short* __restrict__ wgp, unsigned short* __restrict__ wzp,
                       unsigned short* __restrict__ fwp, unsigned short* __restrict__ l1p,
                       unsigned short* __restrict__ l2p, float* __restrict__ sbs) {
    int i = blockIdx.x * blockDim.x + threadIdx.x;
    if (i < 860160) {  // wgp: 30*128*224
        int l = i / 28672, r = i % 28672;
        int o = r / 224, k = r % 224;
        float v;
        if (k < 64)       v = conv_w[(((size_t)l * 128 + o) * 64 + k) * 2 + 0];
        else if (k < 128) v = conv_w[(((size_t)l * 128 + o) * 64 + (k - 64)) * 2 + 1];
        else if (k < 208) v = cond_w[((size_t)l * 128 + o) * 80 + (k - 128)];
        else              v = 0.0f;
        wgp[i] = f2b(v);
        return;
    }
    i -= 860160;
    if (i < 245760) {  // wzp: 30*128*64
        int l = i / 8192, rr = (i % 8192) / 64, k = i % 64;
        float v = (rr < 64) ? skip_w[((size_t)l * 64 + rr) * 64 + k]
                            : out_w[((size_t)l * 64 + (rr - 64)) * 64 + k];
        wzp[i] = f2b(v);
        return;
    }
    i -= 245760;
    if (i < 16384) { fwp[i] = f2b(first_w[i]); return; }   // 64*256
    i -= 16384;
    if (i < 4096) { l1p[i] = f2b(last1_w[i]); return; }    // 64*64
    i -= 4096;
    if (i < 16384) { l2p[i] = f2b(last2_w[i]); return; }   // 256*64
    i -= 16384;
    if (i < 64) {
        float a = 0.f;
        for (int l = 0; l < 30; ++l) a += skip_b[l * 64 + i];
        sbs[i] = a;
    }
}

// ---------------- upsample network ----------------
__global__ void k_convin(const float* __restrict__ c, const float* __restrict__ w,
                         float* __restrict__ c1) {
    int idx = blockIdx.x * blockDim.x + threadIdx.x;
    if (idx >= BATCH * 80 * 400) return;
    int f = idx % 400;
    int o = (idx / 400) % 80;
    int b = idx / (400 * 80);
    const float* cb = c + (size_t)b * 80 * 400 + f;
    const float* wr = w + o * 80;
    float acc = 0.f;
    #pragma unroll 8
    for (int j = 0; j < 80; ++j) acc += wr[j] * cb[(size_t)j * 400];
    c1[idx] = acc;
}

__global__ void k_up0(const float* __restrict__ c1, const float* __restrict__ w,
                      float* __restrict__ c2) {
    int idx = blockIdx.x * blockDim.x + threadIdx.x;
    if (idx >= BATCH * 80 * 4000) return;
    int t = idx % 4000;
    int ch = idx / 4000;
    int u = t / 10, r = t - u * 10;
    float w0 = 0.f, w1 = 0.f, w2 = 0.f;
    #pragma unroll
    for (int j = 0; j < 21; ++j) {
        float wj = w[j];
        int a = r - 10 + j;
        if (a < 0) w0 += wj;
        else if (a < 10) w1 += wj;
        else w2 += wj;
    }
    const float* src = c1 + (size_t)ch * 400;
    float s0 = (u >= 1) ? src[u - 1] : 0.f;
    float s1 = src[u];
    float s2 = (u + 1 < 400) ? src[u + 1] : 0.f;
    c2[idx] = w0 * s0 + w1 * s1 + w2 * s2;
}

__global__ __launch_bounds__(256) void k_up1b(const float* __restrict__ c2,
                                              const float* __restrict__ w,
                                              unsigned short* __restrict__ cupb) {
    __shared__ float S[80][13];
    __shared__ float W[8][4];
    const int b = blockIdx.y, t0 = blockIdx.x * 64;
    const int tid = threadIdx.x;
    const int u0 = t0 >> 3;

    for (int i = tid; i < 800; i += 256) {
        int ch = i / 10, uu = i % 10;
        int u = u0 - 1 + uu;
        float v = 0.f;
        if (u >= 0 && u < 4000) v = c2[((size_t)b * 80 + ch) * 4000 + u];
        S[ch][uu] = v;
    }
    if (tid < 24) {
        int r = tid / 3, k = tid % 3;
        int jlo = (k == 0) ? 0 : (k == 1 ? 8 - r : 16 - r);
        int jhi = (k == 0) ? 7 - r : (k == 1 ? 15 - r : 16);
        float a = 0.f;
        for (int j = jlo; j <= jhi; ++j) a += w[j];
        W[r][k] = a;
    }
    __syncthreads();

    unsigned short* ob = cupb + ((size_t)b * T_TOTAL + t0) * 96;
    for (int i = tid; i < 64 * 96; i += 256) {
        int ch = i % 96;
        int tl = i / 96;
        float acc = 0.f;
        if (ch < 80) {
            int r = tl & 7, ub = tl >> 3;
            acc = W[r][0] * S[ch][ub] + W[r][1] * S[ch][ub + 1] + W[r][2] * S[ch][ub + 2];
        }
        ob[i] = f2b(acc);
    }
}

// ---------------- first 1x1 conv (MFMA), TTF=32 tile for occupancy -----------
#define XFS 266
__global__ __launch_bounds__(256, 8) void k_first(
    const float* __restrict__ x, const unsigned short* __restrict__ fwp,
    const float* __restrict__ fb, float* __restrict__ h0) {
    __shared__ unsigned short Xf[TTF * XFS];
    const int b = blockIdx.y, t0 = blockIdx.x * TTF, tid = threadIdx.x;
    const int lane = tid & 63;
    const int wv = __builtin_amdgcn_readfirstlane(tid >> 6);
    const int l15 = lane & 15, q = lane >> 4;

    // stage + transpose: x is [b][256 ch][T] fp32 -> Xf[t][ch] bf16
    for (int i = tid; i < 2048; i += 256) {
        int ch = i >> 3;            // 0..255
        int t4 = (i & 7) << 2;      // 0,4,...,28
        const float* xr = x + ((size_t)b * 256 + ch) * T_TOTAL + t0 + t4;
        float4 u = *(const float4*)xr;
        int base = t4 * XFS + ch;
        Xf[base + 0 * XFS] = f2b(u.x);
        Xf[base + 1 * XFS] = f2b(u.y);
        Xf[base + 2 * XFS] = f2b(u.z);
        Xf[base + 3 * XFS] = f2b(u.w);
    }
    __syncthreads();

    f32x4 acc[2] = {};
    const unsigned short* wr = fwp + (size_t)(16 * wv + l15) * 256;
    #pragma unroll
    for (int ks = 0; ks < 8; ++ks) {
        bf16x8 aA = ld_bf8(wr + ks * 32 + q * 8);
        #pragma unroll
        for (int tt = 0; tt < 2; ++tt) {
            bf16x8 bb = ld_bf8(&Xf[(tt * 16 + l15) * XFS + ks * 32 + q * 8]);
            acc[tt] = __builtin_amdgcn_mfma_f32_16x16x32_bf16(aA, bb, acc[tt], 0, 0, 0);
        }
    }
    const float4 fbv = *(const float4*)&fb[16 * wv + 4 * q];
    float* hob = h0 + (size_t)b * T_TOTAL * 64;
    #pragma unroll
    for (int tt = 0; tt < 2; ++tt) {
        size_t base = (size_t)(t0 + tt * 16 + l15) * 64 + 16 * wv + 4 * q;
        float4 ho;
        ho.x = acc[tt][0] + fbv.x;
        ho.y = acc[tt][1] + fbv.y;
        ho.z = acc[tt][2] + fbv.z;
        ho.w = acc[tt][3] + fbv.w;
        *(float4*)(hob + base) = ho;
    }
}

// ---------------- fused WaveNet layer (deferred skips: writes z bf16) --------
__global__ __launch_bounds__(256, 4) void k_layer(
    const float* __restrict__ h_in, float* __restrict__ h_out,
    unsigned short* __restrict__ zb_l, const unsigned short* __restrict__ cupb,
    const unsigned short* __restrict__ wgp_l, const unsigned short* __restrict__ wzp_l,
    const float* __restrict__ cb_l, const float* __restrict__ ob_l, int d) {
    __shared__ unsigned short Xl[64 * 224];
    __shared__ unsigned short zs[64 * 72];
    const int b = blockIdx.y, t0 = blockIdx.x * TT, tid = threadIdx.x;
    const int lane = tid & 63;
    const int wv = __builtin_amdgcn_readfirstlane(tid >> 6);
    const int l15 = lane & 15, q = lane >> 4;

    const float* hb = h_in + (size_t)b * T_TOTAL * 64;
    for (int i = tid; i < 512; i += 256) {
        int t = i >> 3, cb8 = (i & 7) << 3;
        const float4* p1 = (const float4*)(hb + (size_t)(t0 + t) * 64 + cb8);
        float4 u0 = p1[0], u1 = p1[1];
        uint4v v1;
        v1.x = f2b2(u0.x, u0.y); v1.y = f2b2(u0.z, u0.w);
        v1.z = f2b2(u1.x, u1.y); v1.w = f2b2(u1.z, u1.w);
        *(uint4v*)&Xl[t * 224 + 64 + cb8] = v1;
        int td = t0 + t - d;
        uint4v v0 = {0u, 0u, 0u, 0u};
        if (td >= 0) {
            const float4* p0 = (const float4*)(hb + (size_t)td * 64 + cb8);
            float4 w0 = p0[0], w1 = p0[1];
            v0.x = f2b2(w0.x, w0.y); v0.y = f2b2(w0.z, w0.w);
            v0.z = f2b2(w1.x, w1.y); v0.w = f2b2(w1.z, w1.w);
        }
        *(uint4v*)&Xl[t * 224 + cb8] = v0;
    }
    const unsigned short* cbb = cupb + (size_t)b * T_TOTAL * 96;
    for (int i = tid; i < 768; i += 256) {
        int t = i / 12, j = (i % 12) << 3;
        *(uint4v*)&Xl[t * 224 + 128 + j] = *(const uint4v*)&cbb[(size_t)(t0 + t) * 96 + j];
    }
    __syncthreads();

    f32x4 accA[4] = {}, accG[4] = {};
    const unsigned short* wrow_a = wgp_l + (size_t)(16 * wv + l15) * 224;
    const unsigned short* wrow_g = wgp_l + (size_t)(64 + 16 * wv + l15) * 224;
    #pragma unroll
    for (int ks = 0; ks < 7; ++ks) {
        bf16x8 aA = ld_bf8(wrow_a + ks * 32 + q * 8);
        bf16x8 aG = ld_bf8(wrow_g + ks * 32 + q * 8);
        #pragma unroll
        for (int tt = 0; tt < 4; ++tt) {
            bf16x8 bb = ld_bf8(&Xl[(tt * 16 + l15) * 224 + ks * 32 + q * 8]);
            accA[tt] = __builtin_amdgcn_mfma_f32_16x16x32_bf16(aA, bb, accA[tt], 0, 0, 0);
            accG[tt] = __builtin_amdgcn_mfma_f32_16x16x32_bf16(aG, bb, accG[tt], 0, 0, 0);
        }
    }
    const float4 cbA = *(const float4*)&cb_l[16 * wv + 4 * q];
    const float4 cbG = *(const float4*)&cb_l[64 + 16 * wv + 4 * q];
    #pragma unroll
    for (int tt = 0; tt < 4; ++tt) {
        int t = tt * 16 + l15;
        float z0 = fast_tanh(accA[tt][0] + cbA.x) * fast_sigmoid(accG[tt][0] + cbG.x);
        float z1 = fast_tanh(accA[tt][1] + cbA.y) * fast_sigmoid(accG[tt][1] + cbG.y);
        float z2 = fast_tanh(accA[tt][2] + cbA.z) * fast_sigmoid(accG[tt][2] + cbG.z);
        float z3 = fast_tanh(accA[tt][3] + cbA.w) * fast_sigmoid(accG[tt][3] + cbG.w);
        uint2v zv;
        zv.x = f2b2(z0, z1);
        zv.y = f2b2(z2, z3);
        *(uint2v*)&zs[t * 72 + 16 * wv + 4 * q] = zv;
    }
    __syncthreads();

    // write z tile to global (coalesced); skip GEMM deferred to k_skips
    unsigned short* zg = zb_l + ((size_t)b * T_TOTAL + t0) * 64;
    #pragma unroll
    for (int it = 0; it < 2; ++it) {
        int i = tid + it * 256;
        int t = i >> 3, c8 = (i & 7) << 3;
        *(uint4v*)&zg[t * 64 + c8] = *(const uint4v*)&zs[t * 72 + c8];
    }

    // out GEMM only (h residual)
    f32x4 accO[4] = {};
    const unsigned short* zrow_o = wzp_l + (size_t)(64 + 16 * wv + l15) * 64;
    #pragma unroll
    for (int ks = 0; ks < 2; ++ks) {
        bf16x8 aO = ld_bf8(zrow_o + ks * 32 + q * 8);
        #pragma unroll
        for (int tt = 0; tt < 4; ++tt) {
            bf16x8 bb = ld_bf8(&zs[(tt * 16 + l15) * 72 + ks * 32 + q * 8]);
            accO[tt] = __builtin_amdgcn_mfma_f32_16x16x32_bf16(aO, bb, accO[tt], 0, 0, 0);
        }
    }
    const float4 obv = *(const float4*)&ob_l[16 * wv + 4 * q];
    float* hob = h_out + (size_t)b * T_TOTAL * 64;
    #pragma unroll
    for (int tt = 0; tt < 4; ++tt) {
        size_t base = (size_t)(t0 + tt * 16 + l15) * 64 + 16 * wv + 4 * q;
        float4 hi = *(const float4*)(hb + base);
        float4 ho;
        ho.x = hi.x + accO[tt][0] + obv.x;
        ho.y = hi.y + accO[tt][1] + obv.y;
        ho.z = hi.z + accO[tt][2] + obv.z;
        ho.w = hi.w + accO[tt][3] + obv.w;
        *(float4*)(hob + base) = ho;
    }
}

// ---------------- fallback full layer (with fp32 skip accumulation) ----------
__global__ __launch_bounds__(256, 4) void k_layer_f(
    const float* __restrict__ h_in, float* __restrict__ h_out,
    float* __restrict__ skips, const unsigned short* __restrict__ cupb,
    const unsigned short* __restrict__ wgp, const unsigned short* __restrict__ wzp,
    const float* __restrict__ cb_l, const float* __restrict__ ob_l,
    const float* __restrict__ sb_l, int d, int first) {
    __shared__ unsigned short Xl[64 * 224];
    __shared__ unsigned short zs[64 * 72];
    const int b = blockIdx.y, t0 = blockIdx.x * TT, tid = threadIdx.x;
    const int lane = tid & 63;
    const int wv = __builtin_amdgcn_readfirstlane(tid >> 6);
    const int l15 = lane & 15, q = lane >> 4;

    const float* hb = h_in + (size_t)b * T_TOTAL * 64;
    for (int i = tid; i < 512; i += 256) {
        int t = i >> 3, cb8 = (i & 7) << 3;
        const float4* p1 = (const float4*)(hb + (size_t)(t0 + t) * 64 + cb8);
        float4 u0 = p1[0], u1 = p1[1];
        uint4v v1;
        v1.x = f2b2(u0.x, u0.y); v1.y = f2b2(u0.z, u0.w);
        v1.z = f2b2(u1.x, u1.y); v1.w = f2b2(u1.z, u1.w);
        *(uint4v*)&Xl[t * 224 + 64 + cb8] = v1;
        int td = t0 + t - d;
        uint4v v0 = {0u, 0u, 0u, 0u};
        if (td >= 0) {
            const float4* p0 = (const float4*)(hb + (size_t)td * 64 + cb8);
            float4 w0 = p0[0], w1 = p0[1];
            v0.x = f2b2(w0.x, w0.y); v0.y = f2b2(w0.z, w0.w);
            v0.z = f2b2(w1.x, w1.y); v0.w = f2b2(w1.z, w1.w);
        }
        *(uint4v*)&Xl[t * 224 + cb8] = v0;
    }
    const unsigned short* cbb = cupb + (size_t)b * T_TOTAL * 96;
    for (int i = tid; i < 768; i += 256) {
        int t = i / 12, j = (i % 12) << 3;
        *(uint4v*)&Xl[t * 224 + 128 + j] = *(const uint4v*)&cbb[(size_t)(t0 + t) * 96 + j];
    }
    __syncthreads();

    f32x4 accA[4] = {}, accG[4] = {};
    const unsigned short* wrow_a = wgp + (size_t)(16 * wv + l15) * 224;
    const unsigned short* wrow_g = wgp + (size_t)(64 + 16 * wv + l15) * 224;
    #pragma unroll
    for (int ks = 0; ks < 7; ++ks) {
        bf16x8 aA = ld_bf8(wrow_a + ks * 32 + q * 8);
        bf16x8 aG = ld_bf8(wrow_g + ks * 32 + q * 8);
        #pragma unroll
        for (int tt = 0; tt < 4; ++tt) {
            bf16x8 bb = ld_bf8(&Xl[(tt * 16 + l15) * 224 + ks * 32 + q * 8]);
            accA[tt] = __builtin_amdgcn_mfma_f32_16x16x32_bf16(aA, bb, accA[tt], 0, 0, 0);
            accG[tt] = __builtin_amdgcn_mfma_f32_16x16x32_bf16(aG, bb, accG[tt], 0, 0, 0);
        }
    }
    const float4 cbA = *(const float4*)&cb_l[16 * wv + 4 * q];
    const float4 cbG = *(const float4*)&cb_l[64 + 16 * wv + 4 * q];
    #pragma unroll
    for (int tt = 0; tt < 4; ++tt) {
        int t = tt * 16 + l15;
        float z0 = fast_tanh(accA[tt][0] + cbA.x) * fast_sigmoid(accG[tt][0] + cbG.x);
        float z1 = fast_tanh(accA[tt][1] + cbA.y) * fast_sigmoid(accG[tt][1] + cbG.y);
        float z2 = fast_tanh(accA[tt][2] + cbA.z) * fast_sigmoid(accG[tt][2] + cbG.z);
        float z3 = fast_tanh(accA[tt][3] + cbA.w) * fast_sigmoid(accG[tt][3] + cbG.w);
        uint2v zv;
        zv.x = f2b2(z0, z1);
        zv.y = f2b2(z2, z3);
        *(uint2v*)&zs[t * 72 + 16 * wv + 4 * q] = zv;
    }
    __syncthreads();

    f32x4 accS[4] = {}, accO[4] = {};
    const unsigned short* zrow_s = wzp + (size_t)(16 * wv + l15) * 64;
    const unsigned short* zrow_o = wzp + (size_t)(64 + 16 * wv + l15) * 64;
    #pragma unroll
    for (int ks = 0; ks < 2; ++ks) {
        bf16x8 aS = ld_bf8(zrow_s + ks * 32 + q * 8);
        bf16x8 aO = ld_bf8(zrow_o + ks * 32 + q * 8);
        #pragma unroll
        for (int tt = 0; tt < 4; ++tt) {
            bf16x8 bb = ld_bf8(&zs[(tt * 16 + l15) * 72 + ks * 32 + q * 8]);
            accS[tt] = __builtin_amdgcn_mfma_f32_16x16x32_bf16(aS, bb, accS[tt], 0, 0, 0);
            accO[tt] = __builtin_amdgcn_mfma_f32_16x16x32_bf16(aO, bb, accO[tt], 0, 0, 0);
        }
    }
    const float4 sbv = *(const float4*)&sb_l[16 * wv + 4 * q];
    const float4 obv = *(const float4*)&ob_l[16 * wv + 4 * q];
    float* hob = h_out + (size_t)b * T_TOTAL * 64;
    float* skb = skips + (size_t)b * T_TOTAL * 64;
    #pragma unroll
    for (int tt = 0; tt < 4; ++tt) {
        size_t base = (size_t)(t0 + tt * 16 + l15) * 64 + 16 * wv + 4 * q;
        float4 hi = *(const float4*)(hb + base);
        float4 ho;
        ho.x = hi.x + accO[tt][0] + obv.x;
        ho.y = hi.y + accO[tt][1] + obv.y;
        ho.z = hi.z + accO[tt][2] + obv.z;
        ho.w = hi.w + accO[tt][3] + obv.w;
        *(float4*)(hob + base) = ho;
        float4 sv;
        if (first) {
            sv.x = accS[tt][0] + sbv.x;
            sv.y = accS[tt][1] + sbv.y;
            sv.z = accS[tt][2] + sbv.z;
            sv.w = accS[tt][3] + sbv.w;
        } else {
            float4 sp = *(const float4*)(skb + base);
            sv.x = sp.x + accS[tt][0] + sbv.x;
            sv.y = sp.y + accS[tt][1] + sbv.y;
            sv.z = sp.z + accS[tt][2] + sbv.z;
            sv.w = sp.w + accS[tt][3] + sbv.w;
        }
        *(float4*)(skb + base) = sv;
    }
}

// ---------------- chunked skip reduction (+ last layers in mode 1) -----------
// mode 0: partial[t][o] = sum_{l in chunk} skip_w[l] @ z_l         (fp32 write)
// mode 1: skips = partial + chunk-sum + sbs ; relu;last1;relu;last2 -> out
__global__ __launch_bounds__(256) void k_skips(
    const unsigned short* __restrict__ zbuf, const unsigned short* __restrict__ wzp_c,
    int nl, float* __restrict__ partial, int mode,
    const float* __restrict__ sbs, const unsigned short* __restrict__ l1p,
    const float* __restrict__ b1, const unsigned short* __restrict__ l2p,
    const float* __restrict__ b2, float* __restrict__ out) {
    __shared__ unsigned short zt[64 * 72];
    __shared__ unsigned short o2s[64 * 72];
    const int b = blockIdx.y, t0 = blockIdx.x * TT, tid = threadIdx.x;
    const int lane = tid & 63;
    const int wv = __builtin_amdgcn_readfirstlane(tid >> 6);
    const int l15 = lane & 15, q = lane >> 4;

    const int st_t = tid >> 3, st_c = (tid & 7) << 3;
    const int st_t2 = (tid + 256) >> 3, st_c2 = ((tid + 256) & 7) << 3;
    const unsigned short* zb = zbuf + ((size_t)b * T_TOTAL + t0) * 64;

    f32x4 acc[4] = {};
    for (int l = 0; l < nl; ++l) {
        const unsigned short* src = zb + (size_t)l * ZSLOT_ELEMS;
        *(uint4v*)&zt[st_t * 72 + st_c] = *(const uint4v*)&src[st_t * 64 + st_c];
        *(uint4v*)&zt[st_t2 * 72 + st_c2] = *(const uint4v*)&src[st_t2 * 64 + st_c2];
        __syncthreads();
        const unsigned short* wr = wzp_c + (size_t)l * 8192 + (size_t)(16 * wv + l15) * 64;
        #pragma unroll
        for (int ks = 0; ks < 2; ++ks) {
            bf16x8 aS = ld_bf8(wr + ks * 32 + q * 8);
            #pragma unroll
            for (int tt = 0; tt < 4; ++tt) {
                bf16x8 bb = ld_bf8(&zt[(tt * 16 + l15) * 72 + ks * 32 + q * 8]);
                acc[tt] = __builtin_amdgcn_mfma_f32_16x16x32_bf16(aS, bb, acc[tt], 0, 0, 0);
            }
        }
        __syncthreads();
    }

    float* pb = partial + (size_t)b * T_TOTAL * 64;
    if (mode == 0) {
        #pragma unroll
        for (int tt = 0; tt < 4; ++tt) {
            size_t base = (size_t)(t0 + tt * 16 + l15) * 64 + 16 * wv + 4 * q;
            float4 sv;
            sv.x = acc[tt][0]; sv.y = acc[tt][1]; sv.z = acc[tt][2]; sv.w = acc[tt][3];
            *(float4*)(pb + base) = sv;
        }
        return;
    }

    // mode 1: add partial + sbs, relu -> zt (bf16)
    const float4 sbv = *(const float4*)&sbs[16 * wv + 4 * q];
    #pragma unroll
    for (int tt = 0; tt < 4; ++tt) {
        int t = tt * 16 + l15;
        size_t base = (size_t)(t0 + t) * 64 + 16 * wv + 4 * q;
        float4 sp = *(const float4*)(pb + base);
        float s0 = fmaxf(sp.x + acc[tt][0] + sbv.x, 0.f);
        float s1 = fmaxf(sp.y + acc[tt][1] + sbv.y, 0.f);
        float s2 = fmaxf(sp.z + acc[tt][2] + sbv.z, 0.f);
        float s3 = fmaxf(sp.w + acc[tt][3] + sbv.w, 0.f);
        uint2v zv;
        zv.x = f2b2(s0, s1);
        zv.y = f2b2(s2, s3);
        *(uint2v*)&zt[t * 72 + 16 * wv + 4 * q] = zv;
    }
    __syncthreads();

    f32x4 a1[4] = {};
    const unsigned short* w1r = l1p + (size_t)(16 * wv + l15) * 64;
    #pragma unroll
    for (int ks = 0; ks < 2; ++ks) {
        bf16x8 aA = ld_bf8(w1r + ks * 32 + q * 8);
        #pragma unroll
        for (int tt = 0; tt < 4; ++tt) {
            bf16x8 bb = ld_bf8(&zt[(tt * 16 + l15) * 72 + ks * 32 + q * 8]);
            a1[tt] = __builtin_amdgcn_mfma_f32_16x16x32_bf16(aA, bb, a1[tt], 0, 0, 0);
        }
    }
    const float4 b1v = *(const float4*)&b1[16 * wv + 4 * q];
    #pragma unroll
    for (int tt = 0; tt < 4; ++tt) {
        int t = tt * 16 + l15;
        float z0 = fmaxf(a1[tt][0] + b1v.x, 0.f);
        float z1 = fmaxf(a1[tt][1] + b1v.y, 0.f);
        float z2 = fmaxf(a1[tt][2] + b1v.z, 0.f);
        float z3 = fmaxf(a1[tt][3] + b1v.w, 0.f);
        uint2v zv;
        zv.x = f2b2(z0, z1);
        zv.y = f2b2(z2, z3);
        *(uint2v*)&o2s[t * 72 + 16 * wv + 4 * q] = zv;
    }
    __syncthreads();

    f32x4 a2[4][4] = {};
    #pragma unroll
    for (int ks = 0; ks < 2; ++ks) {
        bf16x8 aw[4];
        #pragma unroll
        for (int j = 0; j < 4; ++j)
            aw[j] = ld_bf8(l2p + (size_t)(64 * wv + 16 * j + l15) * 64 + ks * 32 + q * 8);
        #pragma unroll
        for (int tt = 0; tt < 4; ++tt) {
            bf16x8 bb = ld_bf8(&o2s[(tt * 16 + l15) * 72 + ks * 32 + q * 8]);
            #pragma unroll
            for (int j = 0; j < 4; ++j)
                a2[j][tt] = __builtin_amdgcn_mfma_f32_16x16x32_bf16(aw[j], bb, a2[j][tt], 0, 0, 0);
        }
    }
    float* ob = out + (size_t)b * 256 * T_TOTAL;
    #pragma unroll
    for (int j = 0; j < 4; ++j) {
        int o0 = 64 * wv + 16 * j + 4 * q;
        float4 b2v = *(const float4*)&b2[o0];
        #pragma unroll
        for (int tt = 0; tt < 4; ++tt) {
            int t = t0 + tt * 16 + l15;
            ob[(size_t)(o0 + 0) * T_TOTAL + t] = a2[j][tt][0] + b2v.x;
            ob[(size_t)(o0 + 1) * T_TOTAL + t] = a2[j][tt][1] + b2v.y;
            ob[(size_t)(o0 + 2) * T_TOTAL + t] = a2[j][tt][2] + b2v.z;
            ob[(size_t)(o0 + 3) * T_TOTAL + t] = a2[j][tt][3] + b2v.w;
        }
    }
}

// ---------------- fallback last layers -----------------
__global__ __launch_bounds__(256) void k_last(
    const float* __restrict__ skips, const unsigned short* __restrict__ l1p,
    const float* __restrict__ b1, const unsigned short* __restrict__ l2p,
    const float* __restrict__ b2, float* __restrict__ out) {
    __shared__ unsigned short sp[64 * 72];
    __shared__ unsigned short o2s[64 * 72];
    const int b = blockIdx.y, t0 = blockIdx.x * TT, tid = threadIdx.x;
    const int lane = tid & 63;
    const int wv = __builtin_amdgcn_readfirstlane(tid >> 6);
    const int l15 = lane & 15, q = lane >> 4;

    const float* skb = skips + (size_t)b * T_TOTAL * 64;
    for (int i = tid; i < 512; i += 256) {
        int t = i >> 3, cb8 = (i & 7) << 3;
        const float4* p = (const float4*)(skb + (size_t)(t0 + t) * 64 + cb8);
        float4 u0 = p[0], u1 = p[1];
        uint4v v;
        v.x = f2b2(fmaxf(u0.x, 0.f), fmaxf(u0.y, 0.f));
        v.y = f2b2(fmaxf(u0.z, 0.f), fmaxf(u0.w, 0.f));
        v.z = f2b2(fmaxf(u1.x, 0.f), fmaxf(u1.y, 0.f));
        v.w = f2b2(fmaxf(u1.z, 0.f), fmaxf(u1.w, 0.f));
        *(uint4v*)&sp[t * 72 + cb8] = v;
    }
    __syncthreads();

    f32x4 a1[4] = {};
    const unsigned short* w1r = l1p + (size_t)(16 * wv + l15) * 64;
    #pragma unroll
    for (int ks = 0; ks < 2; ++ks) {
        bf16x8 aA = ld_bf8(w1r + ks * 32 + q * 8);
        #pragma unroll
        for (int tt = 0; tt < 4; ++tt) {
            bf16x8 bb = ld_bf8(&sp[(tt * 16 + l15) * 72 + ks * 32 + q * 8]);
            a1[tt] = __builtin_amdgcn_mfma_f32_16x16x32_bf16(aA, bb, a1[tt], 0, 0, 0);
        }
    }
    const float4 b1v = *(const float4*)&b1[16 * wv + 4 * q];
    #pragma unroll
    for (int tt = 0; tt < 4; ++tt) {
        int t = tt * 16 + l15;
        float z0 = fmaxf(a1[tt][0] + b1v.x, 0.f);
        float z1 = fmaxf(a1[tt][1] + b1v.y, 0.f);
        float z2 = fmaxf(a1[tt][2] + b1v.z, 0.f);
        float z3 = fmaxf(a1[tt][3] + b1v.w, 0.f);
        uint2v zv;
        zv.x = f2b2(z0, z1);
        zv.y = f2b2(z2, z3);
        *(uint2v*)&o2s[t * 72 + 16 * wv + 4 * q] = zv;
    }
    __syncthreads();

    f32x4 a2[4][4] = {};
    #pragma unroll
    for (int ks = 0; ks < 2; ++ks) {
        bf16x8 aw[4];
        #pragma unroll
        for (int j = 0; j < 4; ++j)
            aw[j] = ld_bf8(l2p + (size_t)(64 * wv + 16 * j + l15) * 64 + ks * 32 + q * 8);
        #pragma unroll
        for (int tt = 0; tt < 4; ++tt) {
            bf16x8 bb = ld_bf8(&o2s[(tt * 16 + l15) * 72 + ks * 32 + q * 8]);
            #pragma unroll
            for (int j = 0; j < 4; ++j)
                a2[j][tt] = __builtin_amdgcn_mfma_f32_16x16x32_bf16(aw[j], bb, a2[j][tt], 0, 0, 0);
        }
    }
    float* ob = out + (size_t)b * 256 * T_TOTAL;
    #pragma unroll
    for (int j = 0; j < 4; ++j) {
        int o0 = 64 * wv + 16 * j + 4 * q;
        float4 b2v = *(const float4*)&b2[o0];
        #pragma unroll
        for (int tt = 0; tt < 4; ++tt) {
            int t = t0 + tt * 16 + l15;
            ob[(size_t)(o0 + 0) * T_TOTAL + t] = a2[j][tt][0] + b2v.x;
            ob[(size_t)(o0 + 1) * T_TOTAL + t] = a2[j][tt][1] + b2v.y;
            ob[(size_t)(o0 + 2) * T_TOTAL + t] = a2[j][tt][2] + b2v.z;
            ob[(size_t)(o0 + 3) * T_TOTAL + t] = a2[j][tt][3] + b2v.w;
        }
    }
}

extern "C" void kernel_launch(void* const* d_in, const int* in_sizes, int n_in,
                              void* d_out, int out_size, void* d_ws, size_t ws_size,
                              hipStream_t stream) {
    const float* x         = (const float*)d_in[0];
    const float* c         = (const float*)d_in[1];
    const float* first_w   = (const float*)d_in[2];
    const float* first_b   = (const float*)d_in[3];
    const float* conv_w    = (const float*)d_in[4];
    const float* conv_b    = (const float*)d_in[5];
    const float* cond_w    = (const float*)d_in[6];
    const float* out_w     = (const float*)d_in[7];
    const float* out_b     = (const float*)d_in[8];
    const float* skip_w    = (const float*)d_in[9];
    const float* skip_b    = (const float*)d_in[10];
    const float* last1_w   = (const float*)d_in[11];
    const float* last1_b   = (const float*)d_in[12];
    const float* last2_w   = (const float*)d_in[13];
    const float* last2_b   = (const float*)d_in[14];
    const float* conv_in_w = (const float*)d_in[15];
    const float* up_w0     = (const float*)d_in[16];
    const float* up_w1     = (const float*)d_in[17];

    // unified workspace layout (fallback uses everything up to zbuf)
    unsigned char* base = (unsigned char*)d_ws;
    float* c1            = (float*)(base + 0);                   //    512,000
    float* c2            = (float*)(base + 512000);              //  5,120,000
    unsigned short* cupb = (unsigned short*)(base + 5632000);    // 24,576,000
    float* hA            = (float*)(base + 30208000);            // 32,768,000
    float* hB            = (float*)(base + 62976000);            // 32,768,000
    float* skipsP        = (float*)(base + 95744000);            // 32,768,000 (fp32 skips / partial)
    unsigned short* wgp  = (unsigned short*)(base + 128512000);  //  1,720,320
    unsigned short* wzp  = (unsigned short*)(base + 130232320);  //    491,520
    unsigned short* fwp  = (unsigned short*)(base + 130723840);  //     32,768
    unsigned short* l1p  = (unsigned short*)(base + 130756608);  //      8,192
    unsigned short* l2p  = (unsigned short*)(base + 130764800);  //     32,768
    float* sbs           = (float*)(base + 130797568);           //        256
    unsigned short* zbuf = (unsigned short*)(base + 130797824);  // 15*16,384,000 = 245,760,000

    const bool big = ws_size >= 376557824ull;  // fits 500 MiB harness workspace

    k_pack<<<(1142848 + 255) / 256, 256, 0, stream>>>(
        conv_w, cond_w, skip_w, out_w, first_w, last1_w, last2_w, skip_b,
        wgp, wzp, fwp, l1p, l2p, sbs);
    k_convin<<<(BATCH * 80 * 400 + 255) / 256, 256, 0, stream>>>(c, conv_in_w, c1);
    k_up0<<<(BATCH * 80 * 4000 + 255) / 256, 256, 0, stream>>>(c1, up_w0, c2);
    dim3 upg(T_TOTAL / 64, BATCH);
    k_up1b<<<upg, 256, 0, stream>>>(c2, up_w1, cupb);

    dim3 gridF(T_TOTAL / TTF, BATCH);
    k_first<<<gridF, 256, 0, stream>>>(x, fwp, first_b, hA);

    dim3 grid(T_TOTAL / TT, BATCH);
    float* hin = hA;
    float* hout = hB;

    if (big) {
        for (int l = 0; l < 30; ++l) {
            int d = 1 << (l % 10);
            int sl = l % ZCHUNK;
            k_layer<<<grid, 256, 0, stream>>>(
                hin, hout, zbuf + (size_t)sl * ZSLOT_ELEMS, cupb,
                wgp + (size_t)l * 128 * 224, wzp + (size_t)l * 128 * 64,
                conv_b + (size_t)l * 128, out_b + (size_t)l * 64, d);
            if (l == ZCHUNK - 1) {
                k_skips<<<grid, 256, 0, stream>>>(zbuf, wzp, ZCHUNK, skipsP, 0,
                                                  sbs, l1p, last1_b, l2p, last2_b,
                                                  (float*)d_out);
            }
            float* tmp = hin; hin = hout; hout = tmp;
        }
        k_skips<<<grid, 256, 0, stream>>>(zbuf, wzp + (size_t)ZCHUNK * 8192, ZCHUNK,
                                          skipsP, 1, sbs, l1p, last1_b, l2p, last2_b,
                                          (float*)d_out);
    } else {
        for (int l = 0; l < 30; ++l) {
            int d = 1 << (l % 10);
            k_layer_f<<<grid, 256, 0, stream>>>(
                hin, hout, skipsP, cupb,
                wgp + (size_t)l * 128 * 224, wzp + (size_t)l * 128 * 64,
                conv_b + (size_t)l * 128, out_b + (size_t)l * 64, skip_b + (size_t)l * 64,
                d, l == 0 ? 1 : 0);
            float* tmp = hin; hin = hout; hout = tmp;
        }
        k_last<<<grid, 256, 0, stream>>>(skipsP, l1p, last1_b, l2p, last2_b, (float*)d_out);
    }
}